// Round 15
// baseline (295.280 us; speedup 1.0000x reference)
//
#include <hip/hip_runtime.h>

#define NROWS 8192
#define DIM   1024
#define EPSF  1e-8f

typedef __attribute__((ext_vector_type(4))) float f32x4;

__device__ __forceinline__ unsigned encf(float f) {
  const unsigned bits = __float_as_uint(f);
  return (bits & 0x80000000u) ? ~bits : (bits | 0x80000000u);
}

// ---------------- Kernel A: row L2-normalize, quantize to fp8 e4m3, init maxenc ----------------
// (identical to R9/R11 — proven absmax 0.0)
extern "C" __global__ __launch_bounds__(256)
void koleo_norm(const float* __restrict__ in, int* __restrict__ xq,
                unsigned* __restrict__ maxenc) {
  const int row = blockIdx.x;
  const int tid = threadIdx.x;
  const float4 v = reinterpret_cast<const float4*>(in + (size_t)row * DIM)[tid];
  float ss = v.x * v.x + v.y * v.y + v.z * v.z + v.w * v.w;
#pragma unroll
  for (int off = 32; off > 0; off >>= 1) ss += __shfl_down(ss, off);
  __shared__ float wsum[4];
  if ((tid & 63) == 0) wsum[tid >> 6] = ss;
  __syncthreads();
  const float total = wsum[0] + wsum[1] + wsum[2] + wsum[3];
  const float scale = 1.0f / (sqrtf(total) + EPSF);
  int p = __builtin_amdgcn_cvt_pk_fp8_f32(v.x * scale, v.y * scale, 0, false);
  p = __builtin_amdgcn_cvt_pk_fp8_f32(v.z * scale, v.w * scale, p, true);
  xq[row * 256 + tid] = p;
  if (row < NROWS / 256) maxenc[row * 256 + tid] = 0u;  // enc(any real dot) > 0
}

// ---- Kernel B: upper-triangle Gram-max, 128x128 fp8, NO-LDS (L2-streamed fragments) ----
// No barriers / vmcnt / DMA in the K-loop: each wave loads its MFMA operands straight
// from global (L2-resident via supertile mapping) and runs free. Latency hidden by
// 16 waves/CU TLP (4 blocks x 4 waves, 128-VGPR cap).
#define BM 128
#define NT  (NROWS / BM)            // 64 tiles per dim
#define NBLK (NT * (NT + 1) / 2)    // 2080 upper-triangle blocks

extern "C" __global__ __launch_bounds__(256, 4)
void koleo_grammax(const char* __restrict__ xq, unsigned* __restrict__ maxenc) {
  __shared__ unsigned smaxr[128];
  __shared__ unsigned smaxc[128];

  const int tid  = threadIdx.x;
  const int lane = tid & 63;
  const int wid  = tid >> 6;
  const int wr   = wid >> 1;     // 0..1: rows wr*64..+63
  const int wc   = wid & 1;      // 0..1: cols wc*64..+63
  const int lr   = lane & 15;
  const int lg   = lane >> 4;

  // XCD swizzle + supertile order (R14-proven: per-XCD working set ~4MB = L2-fit)
  const int sbid = (blockIdx.x % 8) * (NBLK / 8) + blockIdx.x / 8;
  int ti, tj;
  {
    const int SC[11] = {0, 136, 392, 648, 904, 1040, 1296, 1552, 1688, 1944, 2080};
    const int SI[10] = {0, 0, 0, 0, 1, 1, 1, 2, 2, 3};
    const int SJ[10] = {0, 1, 2, 3, 1, 2, 3, 2, 3, 3};
    int st = 0;
#pragma unroll
    for (int k = 1; k < 10; ++k) st += (sbid >= SC[k]);
    const int local = sbid - SC[st];
    const int I = SI[st], J = SJ[st];
    if (I == J) {            // diagonal supertile: 16-row upper triangle (136 blocks)
      int i = 0;
      while ((i + 1) * 16 - ((i + 1) * i) / 2 <= local) ++i;
      const int j = i + (local - (i * 16 - (i * (i - 1)) / 2));
      ti = I * 16 + i; tj = J * 16 + j;
    } else {                 // full 16x16 supertile (256 blocks)
      ti = I * 16 + local / 16; tj = J * 16 + local % 16;
    }
  }

  const int rowBase = ti * BM;
  const int colBase = tj * BM;
  const bool diag = (ti == tj);

  // per-fragment row base pointers (k-offsets fold into load immediates via full unroll)
  const char* pA[4];
  const char* pB[4];
#pragma unroll
  for (int mm = 0; mm < 4; ++mm)
    pA[mm] = xq + (size_t)(rowBase + wr * 64 + mm * 16 + lr) * 1024 + lg * 8;
#pragma unroll
  for (int nn = 0; nn < 4; ++nn)
    pB[nn] = xq + (size_t)(colBase + wc * 64 + nn * 16 + lr) * 1024 + lg * 8;

  f32x4 acc[4][4] = {};

  // 8 K-tiles x 2 halves; operand bytes and accumulation order bitwise-identical
  // to the validated R11 LDS path (XOR involution cancels), so absmax stays 0.
#pragma unroll
  for (int kt = 0; kt < 8; ++kt) {
#pragma unroll
    for (int half = 0; half < 2; ++half) {
      long aS[4][2], bS[4][2];
#pragma unroll
      for (int mm = 0; mm < 4; ++mm)
#pragma unroll
        for (int s = 0; s < 2; ++s)
          aS[mm][s] = *(const long*)(pA[mm] + kt * 128 + half * 64 + s * 32);
#pragma unroll
      for (int nn = 0; nn < 4; ++nn)
#pragma unroll
        for (int s = 0; s < 2; ++s)
          bS[nn][s] = *(const long*)(pB[nn] + kt * 128 + half * 64 + s * 32);
#pragma unroll
      for (int s = 0; s < 2; ++s)
#pragma unroll
        for (int mm = 0; mm < 4; ++mm)
#pragma unroll
          for (int nn = 0; nn < 4; ++nn)
            acc[mm][nn] = __builtin_amdgcn_mfma_f32_16x16x32_fp8_fp8(
                aS[mm][s], bS[nn][s], acc[mm][nn], 0, 0, 0);
    }
  }

  // ---- epilogue: per-row / per-col max with diagonal mask (16x16 C/D layout, proven) ----
  if (tid < 128) { smaxr[tid] = 0u; smaxc[tid] = 0u; }
  __syncthreads();

#pragma unroll
  for (int m = 0; m < 4; ++m) {
#pragma unroll
    for (int rr = 0; rr < 4; ++rr) {
      const int lrow = wr * 64 + m * 16 + lg * 4 + rr;  // C/D: row=(lane>>4)*4+reg
      const int grow = rowBase + lrow;
      float mx = -2.0f;
#pragma unroll
      for (int n = 0; n < 4; ++n) {
        float v = acc[m][n][rr];
        const int gcol = colBase + wc * 64 + n * 16 + lr;  // C/D: col=lane&15
        if (grow == gcol) v = -2.0f;                        // mask self-similarity
        mx = fmaxf(mx, v);
      }
#pragma unroll
      for (int off = 1; off < 16; off <<= 1) mx = fmaxf(mx, __shfl_xor(mx, off));
      if (lr == 0) atomicMax(&smaxr[lrow], encf(mx));
    }
  }
  if (!diag) {  // symmetric fold: col j's max over this block's rows
#pragma unroll
    for (int n = 0; n < 4; ++n) {
      const int lcol = wc * 64 + n * 16 + lr;
      float mx = -2.0f;
#pragma unroll
      for (int m = 0; m < 4; ++m)
#pragma unroll
        for (int rr = 0; rr < 4; ++rr) mx = fmaxf(mx, acc[m][n][rr]);
      mx = fmaxf(mx, __shfl_xor(mx, 16));
      mx = fmaxf(mx, __shfl_xor(mx, 32));
      if (lg == 0) atomicMax(&smaxc[lcol], encf(mx));
    }
  }
  __syncthreads();
  if (tid < 128) {
    atomicMax(&maxenc[rowBase + tid], smaxr[tid]);
    if (!diag) atomicMax(&maxenc[colBase + tid], smaxc[tid]);
  }
}

// ---------------- Kernel C: loss reduction ----------------
extern "C" __global__ __launch_bounds__(1024)
void koleo_loss(const unsigned* __restrict__ maxenc, float* __restrict__ out) {
  const int tid = threadIdx.x;
  float sum = 0.0f;
#pragma unroll
  for (int i = tid; i < NROWS; i += 1024) {
    const unsigned u    = maxenc[i];
    const unsigned bits = (u & 0x80000000u) ? (u & 0x7FFFFFFFu) : ~u;
    const float m = __uint_as_float(bits);
    const float d = sqrtf(fmaxf(2.0f - 2.0f * m, 0.0f)) + EPSF;  // ||x_i - x_nn|| + eps
    sum += logf(d + EPSF);
  }
#pragma unroll
  for (int off = 32; off > 0; off >>= 1) sum += __shfl_down(sum, off);
  __shared__ float wsum[16];
  if ((tid & 63) == 0) wsum[tid >> 6] = sum;
  __syncthreads();
  if (tid == 0) {
    float t = 0.0f;
#pragma unroll
    for (int w = 0; w < 16; ++w) t += wsum[w];
    out[0] = -t / (float)NROWS;
  }
}

extern "C" void kernel_launch(void* const* d_in, const int* in_sizes, int n_in,
                              void* d_out, int out_size, void* d_ws, size_t ws_size,
                              hipStream_t stream) {
  const float* in = (const float*)d_in[0];
  char* xq         = (char*)d_ws;                                        // 8 MB fp8 x
  unsigned* maxenc = (unsigned*)((char*)d_ws + (size_t)NROWS * DIM);     // 32 KB
  float* out = (float*)d_out;

  hipLaunchKernelGGL(koleo_norm,    dim3(NROWS), dim3(256),  0, stream, in, (int*)xq, maxenc);
  hipLaunchKernelGGL(koleo_grammax, dim3(NBLK),  dim3(256),  0, stream, xq, maxenc);
  hipLaunchKernelGGL(koleo_loss,    dim3(1),     dim3(1024), 0, stream, maxenc, out);
}

// Round 16
// 83.440 us; speedup vs baseline: 3.5388x; 3.5388x over previous
//
#include <hip/hip_runtime.h>

#define NROWS 8192
#define DIM   1024
#define EPSF  1e-8f

typedef __attribute__((ext_vector_type(4))) float f32x4;

typedef __attribute__((address_space(1))) void g_void;
typedef __attribute__((address_space(3))) void l_void;

__device__ __forceinline__ void async_copy16(void* lds, const void* g) {
  __builtin_amdgcn_global_load_lds((g_void*)const_cast<void*>(g), (l_void*)lds, 16, 0, 0);
}

__device__ __forceinline__ unsigned encf(float f) {
  const unsigned bits = __float_as_uint(f);
  return (bits & 0x80000000u) ? ~bits : (bits | 0x80000000u);
}

template<int N> __device__ __forceinline__ void vmwait() {
  if constexpr (N == 8)      asm volatile("s_waitcnt vmcnt(8)" ::: "memory");
  else                       asm volatile("s_waitcnt vmcnt(0)" ::: "memory");
}
__device__ __forceinline__ void barf() {
  __builtin_amdgcn_s_barrier();
  asm volatile("" ::: "memory");
}

// ---------------- Kernel A: row L2-normalize, quantize to fp8 e4m3, init maxenc ----------------
// (identical to R9/R11 — proven absmax 0.0)
extern "C" __global__ __launch_bounds__(256)
void koleo_norm(const float* __restrict__ in, int* __restrict__ xq,
                unsigned* __restrict__ maxenc) {
  const int row = blockIdx.x;
  const int tid = threadIdx.x;
  const float4 v = reinterpret_cast<const float4*>(in + (size_t)row * DIM)[tid];
  float ss = v.x * v.x + v.y * v.y + v.z * v.z + v.w * v.w;
#pragma unroll
  for (int off = 32; off > 0; off >>= 1) ss += __shfl_down(ss, off);
  __shared__ float wsum[4];
  if ((tid & 63) == 0) wsum[tid >> 6] = ss;
  __syncthreads();
  const float total = wsum[0] + wsum[1] + wsum[2] + wsum[3];
  const float scale = 1.0f / (sqrtf(total) + EPSF);
  int p = __builtin_amdgcn_cvt_pk_fp8_f32(v.x * scale, v.y * scale, 0, false);
  p = __builtin_amdgcn_cvt_pk_fp8_f32(v.z * scale, v.w * scale, p, true);
  xq[row * 256 + tid] = p;
  if (row < NROWS / 256) maxenc[row * 256 + tid] = 0u;  // enc(any real dot) > 0
}

// -------- Kernel B: R11 (best: dbuf + vmcnt(8) + 2 blocks/CU) + R14 supertile L2 mapping --------
#define BM 128
#define NT  (NROWS / BM)            // 64 tiles per dim
#define NBLK (NT * (NT + 1) / 2)    // 2080 upper-triangle blocks
#define NKT 8                       // 8 K-tiles of 128 fp8 bytes

// stage one 16KB chunk = 128 rows x 128B (one operand, one K-tile), 256 threads.
// XOR-swizzled SOURCE, linear gload_lds dest (R5/R9/R11-proven):
// LDS[row][c] = global[row][c ^ ((row&7)<<4)]
__device__ __forceinline__ void stage_chunk(char* dst, const char* gbase, int kt, int tid) {
#pragma unroll
  for (int l = 0; l < 4; ++l) {
    const int o  = l * 4096 + tid * 16;
    const int so = o ^ (((o >> 7) & 7) << 4);
    async_copy16(dst + o, gbase + (size_t)(so >> 7) * 1024 + kt * 128 + (so & 127));
  }
}

// fp8 16x16x32 fragment reads (R9/R11-proven): lane (lr,lg) kstep s -> 8 bytes at
// row*128 + s*32 + lg*8, XOR'd by (row&7)<<4 == xr (involution cancels the stage swizzle).
#define READ_AB(S0)                                                                   \
  {                                                                                   \
    _Pragma("unroll")                                                                 \
    for (int mm = 0; mm < 4; ++mm)                                                    \
      _Pragma("unroll")                                                               \
      for (int s = 0; s < 2; ++s)                                                     \
        aS[mm][s] = *(const long*)(Lc +                                               \
            (((wr * 64 + mm * 16 + lr) * 128 + ((S0) + s) * 32 + lg * 8) ^ xr));      \
    _Pragma("unroll")                                                                 \
    for (int nn = 0; nn < 4; ++nn)                                                    \
      _Pragma("unroll")                                                               \
      for (int s = 0; s < 2; ++s)                                                     \
        bS[nn][s] = *(const long*)(Lc + 16384 +                                       \
            (((wc * 64 + nn * 16 + lr) * 128 + ((S0) + s) * 32 + lg * 8) ^ xr));      \
  }
#define MFMA2()                                                                       \
  {                                                                                   \
    _Pragma("unroll")                                                                 \
    for (int s = 0; s < 2; ++s)                                                       \
      _Pragma("unroll")                                                               \
      for (int mm = 0; mm < 4; ++mm)                                                  \
        _Pragma("unroll")                                                             \
        for (int nn = 0; nn < 4; ++nn)                                                \
          acc[mm][nn] = __builtin_amdgcn_mfma_f32_16x16x32_fp8_fp8(                   \
              aS[mm][s], bS[nn][s], acc[mm][nn], 0, 0, 0);                            \
  }

// Per K-tile t (buffer Lc): p0 {read ks0-1, MFMA}; p1 {read ks2-3, BAR (all tile-t
// reads precede stores), stage tile t+2 -> Lc (8 loads), vmcnt(8) = tile t+1 complete
// with t+2's 8 loads still in flight, BAR, MFMA}. R7/R9/R11-validated wait arithmetic.
template<bool ST, int V>
__device__ __forceinline__ void ktile(int t, char* Lc,
    const char* gA, const char* gB, int tid, int lane, int wr, int wc,
    long (&aS)[4][2], long (&bS)[4][2], f32x4 (&acc)[4][4]) {
  const int lr = lane & 15, lg = lane >> 4;
  const int xr = (lane & 7) << 4;
  // ---- p0: ksteps 0-1 ----
  READ_AB(0);
  __builtin_amdgcn_s_setprio(1); MFMA2(); __builtin_amdgcn_s_setprio(0);
  // ---- p1: ksteps 2-3 ----
  READ_AB(2);
  barf();                                   // all waves' tile-t reads precede stages
  if constexpr (ST) {
    stage_chunk(Lc,         gA, t + 2, tid);
    stage_chunk(Lc + 16384, gB, t + 2, tid);
  }
  if constexpr (V >= 0) vmwait<V>();        // tile t+1 data complete
  barf();                                   // fence before next tile's reads
  __builtin_amdgcn_s_setprio(1); MFMA2(); __builtin_amdgcn_s_setprio(0);
}

extern "C" __global__ __launch_bounds__(256)
void koleo_grammax(const char* __restrict__ xq, unsigned* __restrict__ maxenc) {
  __shared__ char lds[65536];   // 2 dbuf x (A 16KB + B 16KB) -> 2 blocks/CU

  const int tid  = threadIdx.x;
  const int lane = tid & 63;
  const int wid  = tid >> 6;
  const int wr   = wid >> 1;     // 0..1: rows wr*64..+63
  const int wc   = wid & 1;      // 0..1: cols wc*64..+63
  const int lr   = lane & 15;
  const int lg   = lane >> 4;

  // XCD swizzle + supertile order (R14-proven: per-XCD working set ~4MB = L2-fit,
  // FETCH_SIZE 82 -> 19.5 MB). XCD x owns sbid range [x*260, (x+1)*260).
  const int sbid = (blockIdx.x % 8) * (NBLK / 8) + blockIdx.x / 8;
  int ti, tj;
  {
    const int SC[11] = {0, 136, 392, 648, 904, 1040, 1296, 1552, 1688, 1944, 2080};
    const int SI[10] = {0, 0, 0, 0, 1, 1, 1, 2, 2, 3};
    const int SJ[10] = {0, 1, 2, 3, 1, 2, 3, 2, 3, 3};
    int st = 0;
#pragma unroll
    for (int k = 1; k < 10; ++k) st += (sbid >= SC[k]);
    const int local = sbid - SC[st];
    const int I = SI[st], J = SJ[st];
    if (I == J) {            // diagonal supertile: 16-row upper triangle (136 blocks)
      int i = 0;
      while ((i + 1) * 16 - ((i + 1) * i) / 2 <= local) ++i;
      const int j = i + (local - (i * 16 - (i * (i - 1)) / 2));
      ti = I * 16 + i; tj = J * 16 + j;
    } else {                 // full 16x16 supertile (256 blocks)
      ti = I * 16 + local / 16; tj = J * 16 + local % 16;
    }
  }

  const int rowBase = ti * BM;
  const int colBase = tj * BM;
  const bool diag = (ti == tj);

  const char* gA = xq + (size_t)rowBase * 1024;
  const char* gB = xq + (size_t)colBase * 1024;
  char* L0 = lds;
  char* L1 = lds + 32768;

  f32x4 acc[4][4] = {};
  long  aS[4][2];
  long  bS[4][2];

  // prologue: tile 0 -> L0 (8 loads), tile 1 -> L1 (8 loads)
  stage_chunk(L0,         gA, 0, tid);
  stage_chunk(L0 + 16384, gB, 0, tid);
  stage_chunk(L1,         gA, 1, tid);
  stage_chunk(L1 + 16384, gB, 1, tid);
  vmwait<8>();   // tile 0 complete; tile 1's 8 loads in flight
  barf();

#pragma unroll 1
  for (int t2 = 0; t2 < 6; t2 += 2) {
    ktile<true, 8>(t2,     L0, gA, gB, tid, lane, wr, wc, aS, bS, acc);
    ktile<true, 8>(t2 + 1, L1, gA, gB, tid, lane, wr, wc, aS, bS, acc);
  }
  ktile<false, 0>(6, L0, gA, gB, tid, lane, wr, wc, aS, bS, acc);   // drain tile-7 loads
  ktile<false, -1>(7, L1, gA, gB, tid, lane, wr, wc, aS, bS, acc);

  // ---- epilogue: per-row / per-col max with diagonal mask (16x16 C/D layout, proven) ----
  __syncthreads();
  unsigned* smaxr = (unsigned*)lds;           // [128]
  unsigned* smaxc = (unsigned*)(lds + 512);   // [128]
  if (tid < 128) { smaxr[tid] = 0u; smaxc[tid] = 0u; }
  __syncthreads();

#pragma unroll
  for (int m = 0; m < 4; ++m) {
#pragma unroll
    for (int rr = 0; rr < 4; ++rr) {
      const int lrow = wr * 64 + m * 16 + lg * 4 + rr;  // C/D: row=(lane>>4)*4+reg
      const int grow = rowBase + lrow;
      float mx = -2.0f;
#pragma unroll
      for (int n = 0; n < 4; ++n) {
        float v = acc[m][n][rr];
        const int gcol = colBase + wc * 64 + n * 16 + lr;  // C/D: col=lane&15
        if (grow == gcol) v = -2.0f;                        // mask self-similarity
        mx = fmaxf(mx, v);
      }
#pragma unroll
      for (int off = 1; off < 16; off <<= 1) mx = fmaxf(mx, __shfl_xor(mx, off));
      if (lr == 0) atomicMax(&smaxr[lrow], encf(mx));
    }
  }
  if (!diag) {  // symmetric fold: col j's max over this block's rows
#pragma unroll
    for (int n = 0; n < 4; ++n) {
      const int lcol = wc * 64 + n * 16 + lr;
      float mx = -2.0f;
#pragma unroll
      for (int m = 0; m < 4; ++m)
#pragma unroll
        for (int rr = 0; rr < 4; ++rr) mx = fmaxf(mx, acc[m][n][rr]);
      mx = fmaxf(mx, __shfl_xor(mx, 16));
      mx = fmaxf(mx, __shfl_xor(mx, 32));
      if (lg == 0) atomicMax(&smaxc[lcol], encf(mx));
    }
  }
  __syncthreads();
  if (tid < 128) {
    atomicMax(&maxenc[rowBase + tid], smaxr[tid]);
    if (!diag) atomicMax(&maxenc[colBase + tid], smaxc[tid]);
  }
}

// ---------------- Kernel C: loss reduction ----------------
extern "C" __global__ __launch_bounds__(1024)
void koleo_loss(const unsigned* __restrict__ maxenc, float* __restrict__ out) {
  const int tid = threadIdx.x;
  float sum = 0.0f;
#pragma unroll
  for (int i = tid; i < NROWS; i += 1024) {
    const unsigned u    = maxenc[i];
    const unsigned bits = (u & 0x80000000u) ? (u & 0x7FFFFFFFu) : ~u;
    const float m = __uint_as_float(bits);
    const float d = sqrtf(fmaxf(2.0f - 2.0f * m, 0.0f)) + EPSF;  // ||x_i - x_nn|| + eps
    sum += logf(d + EPSF);
  }
#pragma unroll
  for (int off = 32; off > 0; off >>= 1) sum += __shfl_down(sum, off);
  __shared__ float wsum[16];
  if ((tid & 63) == 0) wsum[tid >> 6] = sum;
  __syncthreads();
  if (tid == 0) {
    float t = 0.0f;
#pragma unroll
    for (int w = 0; w < 16; ++w) t += wsum[w];
    out[0] = -t / (float)NROWS;
  }
}

extern "C" void kernel_launch(void* const* d_in, const int* in_sizes, int n_in,
                              void* d_out, int out_size, void* d_ws, size_t ws_size,
                              hipStream_t stream) {
  const float* in = (const float*)d_in[0];
  char* xq         = (char*)d_ws;                                        // 8 MB fp8 x
  unsigned* maxenc = (unsigned*)((char*)d_ws + (size_t)NROWS * DIM);     // 32 KB
  float* out = (float*)d_out;

  hipLaunchKernelGGL(koleo_norm,    dim3(NROWS), dim3(256),  0, stream, in, (int*)xq, maxenc);
  hipLaunchKernelGGL(koleo_grammax, dim3(NBLK),  dim3(256),  0, stream, xq, maxenc);
  hipLaunchKernelGGL(koleo_loss,    dim3(1),     dim3(1024), 0, stream, maxenc, out);
}